// Round 1
// baseline (216.725 us; speedup 1.0000x reference)
//
#include <hip/hip_runtime.h>
#include <math.h>

typedef unsigned short u16;
typedef unsigned int   u32;
typedef __attribute__((ext_vector_type(8))) short short8;
typedef __attribute__((ext_vector_type(4))) float f32x4;

namespace {
constexpr int Bb = 32, Nn = 32, Ll = 512, Mm = 64, Ff = 64;
constexpr int TL  = 32;           // K-tile in l (= one MFMA K step)
constexpr int NT  = Ll / TL;      // 16
constexpr int TLP = 40;           // padded row (u16): 80B stride
constexpr float EPSV = 1e-8f;
constexpr size_t A_ELEMS = (size_t)Nn * Ll * Mm;   // u16 per alpha plane (1 Mi)
}

__device__ __forceinline__ u16 bf16rne(float x) {
    u32 u = __float_as_uint(x);
    return (u16)((u + 0x7fffu + ((u >> 16) & 1u)) >> 16);
}
__device__ __forceinline__ float bf16tof(u16 h) {
    return __uint_as_float(((u32)h) << 16);
}

// Raw barrier: drain LDS writes only; global loads stay in flight (vmcnt not
// drained, unlike __syncthreads). "memory" clobbers pin compiler-visible
// shared-mem ops on the correct side.
__device__ __forceinline__ void lgkm_barrier() {
    asm volatile("s_waitcnt lgkmcnt(0)" ::: "memory");
    __builtin_amdgcn_s_barrier();
    asm volatile("" ::: "memory");
}

// ---------------------------------------------------------------------------
// Kernel 1: alpha precompute. One block per n. Reproduces the fused kernel's
// per-(ma,lqa) alpha math, bf16 hi/lo splits, dsum accumulation order and the
// lqa 0..3 reduce order BIT-EXACTLY, so the final output is bit-identical.
// Stores alpha in MFMA-fragment order: [n][tile][lq][m][8 u16].
// ---------------------------------------------------------------------------
__global__ __launch_bounds__(256, 4)
void wagg_alpha(const float* __restrict__ t_in,
                const float* __restrict__ t_left,
                const float* __restrict__ t_right,
                const float* __restrict__ kappa,
                u16* __restrict__ Ahi, u16* __restrict__ Alo,
                float* __restrict__ inv_g)
{
    const int n   = blockIdx.x;
    const int tid = threadIdx.x;
    const int ma  = tid >> 2;     // m row
    const int lqa = tid & 3;      // l chunk-of-8 within tile

    __shared__ float dred[256];

    const float kap = kappa[n];
    const float kk  = fmaxf(kap, 0.0f) + log1pf(expf(-fabsf(kap))); // softplus
    const float ik  = 1.0f / kk;
    const float tlv = t_left [n * Mm + ma];
    const float trv = t_right[n * Mm + ma];
    const float Ac  = __expf(-trv * ik);
    const float Bc  = __expf( tlv * ik);

    float dsum = 0.0f;
    for (int t = 0; t < NT; ++t) {
        float T[8];
        *(float4*)&T[0] = *(const float4*)&t_in[t * TL + lqa * 8];
        *(float4*)&T[4] = *(const float4*)&t_in[t * TL + lqa * 8 + 4];
        u32 hi[4], lo[4];
        #pragma unroll
        for (int jj = 0; jj < 8; jj += 2) {
            const float u0 = __expf(T[jj]     * ik);
            const float u1 = __expf(T[jj + 1] * ik);
            const float d0 = fmaf(Ac, u0, 1.0f) * (u0 + Bc);
            const float d1 = fmaf(Ac, u1, 1.0f) * (u1 + Bc);
            const float a0 = u0 * __builtin_amdgcn_rcpf(d0);
            const float a1 = u1 * __builtin_amdgcn_rcpf(d1);
            dsum += a0 + a1;
            const u16 h0 = bf16rne(a0), h1 = bf16rne(a1);
            const u16 s0 = bf16rne(a0 - bf16tof(h0)), s1 = bf16rne(a1 - bf16tof(h1));
            hi[jj >> 1] = (u32)h0 | ((u32)h1 << 16);
            lo[jj >> 1] = (u32)s0 | ((u32)s1 << 16);
        }
        const size_t off = ((((size_t)n * NT + t) * 4 + lqa) * Mm + ma) * 8;
        *(uint4*)&Ahi[off] = make_uint4(hi[0], hi[1], hi[2], hi[3]);
        *(uint4*)&Alo[off] = make_uint4(lo[0], lo[1], lo[2], lo[3]);
    }

    dred[lqa * 64 + ma] = dsum;
    __syncthreads();
    if (tid < Mm) {
        const float d = dred[tid] + dred[64 + tid] + dred[128 + tid] + dred[192 + tid];
        inv_g[n * Mm + tid] = __builtin_amdgcn_rcpf(d + EPSV);
    }
}

// ---------------------------------------------------------------------------
// Kernel 2: main GEMM. Block = (b,n), grid 1024, 256 thr, 20.5 KB LDS (x only).
// alpha fragments read directly from global (L2-resident, fragment-ordered).
// x: 2-tile-deep register prefetch (XA/XB parity sets), chunk-XOR-swizzled LDS
// (2-way conflicts on both ds_write_b32 and ds_read_b128), lgkm-only barriers.
// ---------------------------------------------------------------------------
__global__ __launch_bounds__(256, 4)
void wagg_main(const float* __restrict__ x_aug,
               const u16* __restrict__ Ahi, const u16* __restrict__ Alo,
               const float* __restrict__ inv_g,
               float* __restrict__ out)
{
    const int n   = blockIdx.x & 31;
    const int b   = blockIdx.x >> 5;
    const int tid = threadIdx.x;

    __shared__ u16 xh_s[2][Ff * TLP];       // x-hi [f][l-swizzled]  10.25 KB
    __shared__ u16 xl_s[2][Ff * TLP];       // x-lo                  10.25 KB

    // ---- x staging ids ----
    const int fq  = tid & 15;               // f quad (f = 4*fq + j)
    const int lp2 = tid >> 4;               // l pair: l = 2*lp2, 2*lp2+1
    // write swizzle: row r = 4*fq+j  =>  (r>>3)&3 == (fq>>1)&3 for all j in 0..3
    const int sw   = (fq >> 1) & 3;
    const u32 wbase = (u32)(((lp2 >> 2) ^ sw) * 8 + (lp2 & 3) * 2);

    // ---- MFMA ids ----
    const int wv = tid >> 6, lane = tid & 63;
    const int mh = wv & 1;                  // m base = mh*32
    const int fh = wv >> 1;                 // f base = fh*32
    const int q  = lane >> 4;               // k-chunk / D-row-quad
    const int c  = lane & 15;               // A/B row select / D-col

    const float* xb = x_aug + (size_t)(b * Nn + n) * (Ll * Ff);

    f32x4 acc[2][2];
    #pragma unroll
    for (int mi = 0; mi < 2; ++mi)
        #pragma unroll
        for (int fi = 0; fi < 2; ++fi)
            acc[mi][fi] = (f32x4){0.f, 0.f, 0.f, 0.f};

    float XA0[4], XA1[4], XB0[4], XB1[4];   // parity-named prefetch sets

#define LOADX(X0_, X1_, T_) { \
    const float* p_ = xb + (size_t)((T_) * TL + 2 * lp2) * Ff + fq * 4; \
    *(float4*)(X0_) = *(const float4*)p_; \
    *(float4*)(X1_) = *(const float4*)(p_ + Ff); }

#define STAGEX(BUF_, X0_, X1_) { \
    _Pragma("unroll") \
    for (int j = 0; j < 4; ++j) { \
        const float v0 = (X0_)[j], v1 = (X1_)[j]; \
        const u16 h0 = bf16rne(v0), h1 = bf16rne(v1); \
        const u16 s0 = bf16rne(v0 - bf16tof(h0)), s1 = bf16rne(v1 - bf16tof(h1)); \
        const u32 off_ = (u32)(fq * 4 + j) * TLP + wbase; \
        *(u32*)&xh_s[BUF_][off_] = (u32)h0 | ((u32)h1 << 16); \
        *(u32*)&xl_s[BUF_][off_] = (u32)s0 | ((u32)s1 << 16); } }

#define TILE(T_, CUR_, XS0_, XS1_, XL0_, XL1_) { \
    short8 ahf[2], alf[2], xhf[2], xlf[2]; \
    const u16* ab_ = Ahi + ((((size_t)n * NT + (T_)) * 4 + q) * Mm) * 8; \
    const u16* lb_ = Alo + ((((size_t)n * NT + (T_)) * 4 + q) * Mm) * 8; \
    _Pragma("unroll") \
    for (int mi = 0; mi < 2; ++mi) { \
        const int row_ = mh * 32 + mi * 16 + c; \
        ahf[mi] = *(const short8*)(ab_ + row_ * 8); \
        alf[mi] = *(const short8*)(lb_ + row_ * 8); } \
    if ((T_) + 2 < NT) LOADX(XL0_, XL1_, (T_) + 2); \
    _Pragma("unroll") \
    for (int fi = 0; fi < 2; ++fi) { \
        const int row_ = fh * 32 + fi * 16 + c; \
        const u32 off_ = (u32)row_ * TLP + (u32)((q ^ ((row_ >> 3) & 3)) * 8); \
        xhf[fi] = *(const short8*)&xh_s[CUR_][off_]; \
        xlf[fi] = *(const short8*)&xl_s[CUR_][off_]; } \
    _Pragma("unroll") \
    for (int mi = 0; mi < 2; ++mi) \
        _Pragma("unroll") \
        for (int fi = 0; fi < 2; ++fi) { \
            acc[mi][fi] = __builtin_amdgcn_mfma_f32_16x16x32_bf16(ahf[mi], xhf[fi], acc[mi][fi], 0, 0, 0); \
            acc[mi][fi] = __builtin_amdgcn_mfma_f32_16x16x32_bf16(ahf[mi], xlf[fi], acc[mi][fi], 0, 0, 0); \
            acc[mi][fi] = __builtin_amdgcn_mfma_f32_16x16x32_bf16(alf[mi], xhf[fi], acc[mi][fi], 0, 0, 0); } \
    if ((T_) + 1 < NT) STAGEX((CUR_) ^ 1, XS0_, XS1_); \
    lgkm_barrier(); }

    // ---- prologue ----
    LOADX(XA0, XA1, 0);
    STAGEX(0, XA0, XA1);
    LOADX(XB0, XB1, 1);
    lgkm_barrier();

    for (int tt = 0; tt < NT / 2; ++tt) {
        const int t0 = 2 * tt;
        TILE(t0,     0, XB0, XB1, XA0, XA1);   // stages t0+1 from XB, loads t0+2 into XA
        TILE(t0 + 1, 1, XA0, XA1, XB0, XB1);   // stages t0+2 from XA, loads t0+3 into XB
    }

#undef TILE
#undef STAGEX
#undef LOADX

    // ---- epilogue: scale by precomputed 1/(denom+eps), store ----
    const float* ivp = inv_g + n * Mm;
    float* ob = out + (size_t)(b * Nn + n) * (Mm * Ff);
    #pragma unroll
    for (int mi = 0; mi < 2; ++mi) {
        const int mbase = mh * 32 + mi * 16 + q * 4;
        float iv[4];
        *(float4*)iv = *(const float4*)&ivp[mbase];
        #pragma unroll
        for (int fi = 0; fi < 2; ++fi) {
            const int f = fh * 32 + fi * 16 + c;
            #pragma unroll
            for (int r = 0; r < 4; ++r)
                ob[(size_t)(mbase + r) * Ff + f] = acc[mi][fi][r] * iv[r];
        }
    }
}

// ---------------------------------------------------------------------------
// Fallback: previous fused kernel (verbatim), used only if workspace is small.
// ---------------------------------------------------------------------------
__global__ __launch_bounds__(256, 4)
void wagg_fused(const float* __restrict__ x_aug,
                const float* __restrict__ t_in,
                const float* __restrict__ t_left,
                const float* __restrict__ t_right,
                const float* __restrict__ kappa,
                float* __restrict__ out)
{
    const int n   = blockIdx.x & 31;
    const int b   = blockIdx.x >> 5;
    const int tid = threadIdx.x;

    __shared__ u16 ah_s[2][Mm * TLP];
    __shared__ u16 al_s[2][Mm * TLP];
    __shared__ u16 xh_s[2][Ff * TLP];
    __shared__ u16 xl_s[2][Ff * TLP];

    const int fq  = tid & 15;
    const int lp2 = tid >> 4;
    const int wv   = tid >> 6;
    const int lane = tid & 63;
    const int ma   = wv * 16 + (lane >> 2);
    const int lqa  = lane & 3;
    const int mh = wv & 1;
    const int fh = wv >> 1;
    const int q  = lane >> 4;
    const int c  = lane & 15;

    const float* xb = x_aug + (size_t)(b * Nn + n) * (Ll * Ff);

    const float kap = kappa[n];
    const float kk  = fmaxf(kap, 0.0f) + log1pf(expf(-fabsf(kap)));
    const float ik  = 1.0f / kk;
    const float tlv = t_left [n * Mm + ma];
    const float trv = t_right[n * Mm + ma];
    const float Ac  = __expf(-trv * ik);
    const float Bc  = __expf( tlv * ik);

    f32x4 acc[2][2];
    #pragma unroll
    for (int mi = 0; mi < 2; ++mi)
        #pragma unroll
        for (int fi = 0; fi < 2; ++fi)
            acc[mi][fi] = (f32x4){0.f, 0.f, 0.f, 0.f};

    float X0[4], X1[4];
    float T[8];
    float dsum = 0.0f;

    auto stage = [&](int buf) {
        #pragma unroll
        for (int j = 0; j < 4; ++j) {
            const float v0 = X0[j], v1 = X1[j];
            const u16 h0 = bf16rne(v0), h1 = bf16rne(v1);
            const u16 s0 = bf16rne(v0 - bf16tof(h0)), s1 = bf16rne(v1 - bf16tof(h1));
            const u32 off = (u32)(fq * 4 + j) * TLP + 2 * lp2;
            *(u32*)&xh_s[buf][off] = (u32)h0 | ((u32)h1 << 16);
            *(u32*)&xl_s[buf][off] = (u32)s0 | ((u32)s1 << 16);
        }
        u32 hi[4], lo[4];
        #pragma unroll
        for (int jj = 0; jj < 8; jj += 2) {
            const float u0 = __expf(T[jj]     * ik);
            const float u1 = __expf(T[jj + 1] * ik);
            const float d0 = fmaf(Ac, u0, 1.0f) * (u0 + Bc);
            const float d1 = fmaf(Ac, u1, 1.0f) * (u1 + Bc);
            const float a0 = u0 * __builtin_amdgcn_rcpf(d0);
            const float a1 = u1 * __builtin_amdgcn_rcpf(d1);
            dsum += a0 + a1;
            const u16 h0 = bf16rne(a0), h1 = bf16rne(a1);
            const u16 s0 = bf16rne(a0 - bf16tof(h0)), s1 = bf16rne(a1 - bf16tof(h1));
            hi[jj >> 1] = (u32)h0 | ((u32)h1 << 16);
            lo[jj >> 1] = (u32)s0 | ((u32)s1 << 16);
        }
        const u32 aoff = (u32)ma * TLP + lqa * 8;
        *(uint4*)&ah_s[buf][aoff] = make_uint4(hi[0], hi[1], hi[2], hi[3]);
        *(uint4*)&al_s[buf][aoff] = make_uint4(lo[0], lo[1], lo[2], lo[3]);
    };

    {
        const float* p = xb + (size_t)(2 * lp2) * Ff + fq * 4;
        *(float4*)X0 = *(const float4*)p;
        *(float4*)X1 = *(const float4*)(p + Ff);
        *(float4*)&T[0] = *(const float4*)&t_in[lqa * 8];
        *(float4*)&T[4] = *(const float4*)&t_in[lqa * 8 + 4];
        stage(0);
    }
    __syncthreads();

    for (int tile = 0; tile < NT; ++tile) {
        const int cur = tile & 1, nxt = cur ^ 1;

        if (tile + 1 < NT) {
            const int l0 = (tile + 1) * TL;
            const float* p = xb + (size_t)(l0 + 2 * lp2) * Ff + fq * 4;
            *(float4*)X0 = *(const float4*)p;
            *(float4*)X1 = *(const float4*)(p + Ff);
            *(float4*)&T[0] = *(const float4*)&t_in[l0 + lqa * 8];
            *(float4*)&T[4] = *(const float4*)&t_in[l0 + lqa * 8 + 4];
        }

        short8 ahf[2], alf[2], xhf[2], xlf[2];
        #pragma unroll
        for (int mi = 0; mi < 2; ++mi) {
            const u32 off = (u32)(mh * 32 + mi * 16 + c) * TLP + q * 8;
            ahf[mi] = *(const short8*)&ah_s[cur][off];
            alf[mi] = *(const short8*)&al_s[cur][off];
        }
        #pragma unroll
        for (int fi = 0; fi < 2; ++fi) {
            const u32 off = (u32)(fh * 32 + fi * 16 + c) * TLP + q * 8;
            xhf[fi] = *(const short8*)&xh_s[cur][off];
            xlf[fi] = *(const short8*)&xl_s[cur][off];
        }
        #pragma unroll
        for (int mi = 0; mi < 2; ++mi)
            #pragma unroll
            for (int fi = 0; fi < 2; ++fi) {
                acc[mi][fi] = __builtin_amdgcn_mfma_f32_16x16x32_bf16(
                    ahf[mi], xhf[fi], acc[mi][fi], 0, 0, 0);
                acc[mi][fi] = __builtin_amdgcn_mfma_f32_16x16x32_bf16(
                    ahf[mi], xlf[fi], acc[mi][fi], 0, 0, 0);
                acc[mi][fi] = __builtin_amdgcn_mfma_f32_16x16x32_bf16(
                    alf[mi], xhf[fi], acc[mi][fi], 0, 0, 0);
            }

        if (tile + 1 < NT) stage(nxt);
        __syncthreads();
    }

    float* dred = (float*)&xh_s[0][0];
    float* invp = dred + 256;
    dred[lqa * 64 + ma] = dsum;
    __syncthreads();
    if (tid < Mm) {
        const float d = dred[tid] + dred[64 + tid] + dred[128 + tid] + dred[192 + tid];
        invp[tid] = __builtin_amdgcn_rcpf(d + EPSV);
    }
    __syncthreads();

    float* ob = out + (size_t)(b * Nn + n) * (Mm * Ff);
    #pragma unroll
    for (int mi = 0; mi < 2; ++mi) {
        const int mbase = mh * 32 + mi * 16 + q * 4;
        float iv[4];
        #pragma unroll
        for (int r = 0; r < 4; ++r) iv[r] = invp[mbase + r];
        #pragma unroll
        for (int fi = 0; fi < 2; ++fi) {
            const int f = fh * 32 + fi * 16 + c;
            #pragma unroll
            for (int r = 0; r < 4; ++r)
                ob[(size_t)(mbase + r) * Ff + f] = acc[mi][fi][r] * iv[r];
        }
    }
}

extern "C" void kernel_launch(void* const* d_in, const int* in_sizes, int n_in,
                              void* d_out, int out_size, void* d_ws, size_t ws_size,
                              hipStream_t stream)
{
    const float* x_aug   = (const float*)d_in[0];
    const float* t_in    = (const float*)d_in[1];
    const float* t_left  = (const float*)d_in[2];
    const float* t_right = (const float*)d_in[3];
    const float* kappa   = (const float*)d_in[4];
    float* out = (float*)d_out;

    const size_t need = 2 * A_ELEMS * sizeof(u16) + (size_t)Nn * Mm * sizeof(float);
    if (d_ws != nullptr && ws_size >= need) {
        u16*   Ahi   = (u16*)d_ws;
        u16*   Alo   = Ahi + A_ELEMS;
        float* inv_g = (float*)(Alo + A_ELEMS);
        hipLaunchKernelGGL(wagg_alpha, dim3(Nn), dim3(256), 0, stream,
                           t_in, t_left, t_right, kappa, Ahi, Alo, inv_g);
        hipLaunchKernelGGL(wagg_main, dim3(Bb * Nn), dim3(256), 0, stream,
                           x_aug, Ahi, Alo, inv_g, out);
    } else {
        hipLaunchKernelGGL(wagg_fused, dim3(Bb * Nn), dim3(256), 0, stream,
                           x_aug, t_in, t_left, t_right, kappa, out);
    }
}

// Round 2
// 207.231 us; speedup vs baseline: 1.0458x; 1.0458x over previous
//
#include <hip/hip_runtime.h>
#include <math.h>

typedef unsigned short u16;
typedef unsigned int   u32;
typedef __attribute__((ext_vector_type(8))) short short8;
typedef __attribute__((ext_vector_type(4))) float f32x4;

namespace {
constexpr int Bb = 32, Nn = 32, Ll = 512, Mm = 64, Ff = 64;
constexpr int TL  = 32;           // K-tile in l (= one MFMA K step)
constexpr int NT  = Ll / TL;      // 16
constexpr int TLP = 40;           // padded row (u16): 80B stride
constexpr float EPSV = 1e-8f;
}

__device__ __forceinline__ u16 bf16rne(float x) {
    u32 u = __float_as_uint(x);
    return (u16)((u + 0x7fffu + ((u >> 16) & 1u)) >> 16);
}
__device__ __forceinline__ float bf16tof(u16 h) {
    return __uint_as_float(((u32)h) << 16);
}

// Barrier that drains LDS ops only. Unlike __syncthreads (which emits
// s_waitcnt vmcnt(0)), outstanding global loads stay in flight across it —
// required for the 2-tile-deep x register prefetch to actually overlap HBM
// latency. Mechanics verified in round 1 (passed, bit-identical output).
__device__ __forceinline__ void lgkm_barrier() {
    asm volatile("s_waitcnt lgkmcnt(0)" ::: "memory");
    __builtin_amdgcn_s_barrier();
    asm volatile("" ::: "memory");
}

// ---------------------------------------------------------------------------
// Fused kernel, round-0 structure (alpha computed per-block, staged in LDS)
// with three grafts isolated from the round-1 regression:
//   1. x staging writes XOR-swizzled: l-chunk ^= (f_row>>3)&3  => 2-way
//      bank aliasing (free) instead of 8-way (2.9x issue cost).
//   2. lgkm-only barriers (no vmcnt drain).
//   3. Depth-2 x prefetch via XA/XB parity register sets: loads for tile t+2
//      issued at tile t, consumed by stage at end of tile t+1 (~2 full MFMA
//      sections of latency cover instead of <1).
// Alpha math, dsum accumulation order, MFMA order: byte-identical to round-0
// => output bit-identical (absmax must stay 0.0009765625).
// ---------------------------------------------------------------------------
__global__ __launch_bounds__(256, 4)
void wagg_fused2(const float* __restrict__ x_aug,
                 const float* __restrict__ t_in,
                 const float* __restrict__ t_left,
                 const float* __restrict__ t_right,
                 const float* __restrict__ kappa,
                 float* __restrict__ out)
{
    const int n   = blockIdx.x & 31;
    const int b   = blockIdx.x >> 5;
    const int tid = threadIdx.x;

    __shared__ u16 ah_s[2][Mm * TLP];        // alpha-hi [m][l]   5 KB/stage
    __shared__ u16 al_s[2][Mm * TLP];        // alpha-lo
    __shared__ u16 xh_s[2][Ff * TLP];        // x-hi     [f][l-swizzled]
    __shared__ u16 xl_s[2][Ff * TLP];        // x-lo              total 40 KB

    // ---- x staging ids: lane strip over f, row pair over l ----
    const int fq  = tid & 15;                // f quad (f = 4*fq + j)
    const int lp2 = tid >> 4;                // 0..15 -> l = 2*lp2, 2*lp2+1
    // write swizzle: row r = 4*fq+j  =>  (r>>3)&3 == (fq>>1)&3 for all j
    const int sw    = (fq >> 1) & 3;
    const u32 wbase = (u32)(((lp2 >> 2) ^ sw) * 8 + (lp2 & 3) * 2);

    // ---- alpha ids: wave wv covers m in [wv*16, wv*16+16) ----
    const int wv   = tid >> 6;
    const int lane = tid & 63;
    const int ma   = wv * 16 + (lane >> 2);  // this thread's m
    const int lqa  = lane & 3;               // l chunk: l = lqa*8 + 0..7

    // ---- MFMA ids: wave = (m-half, f-half), 2x2 16x16 tiles ----
    const int mh = wv & 1;                   // m base = mh*32
    const int fh = wv >> 1;                  // f base = fh*32
    const int q  = lane >> 4;                // k-chunk / D-row-quad
    const int c  = lane & 15;                // A/B row select / D-col

    const float* xb = x_aug + (size_t)(b * Nn + n) * (Ll * Ff);

    // ---- prologue scalars ----
    const float kap = kappa[n];
    const float kk  = fmaxf(kap, 0.0f) + log1pf(expf(-fabsf(kap))); // softplus
    const float ik  = 1.0f / kk;
    const float tlv = t_left [n * Mm + ma];
    const float trv = t_right[n * Mm + ma];
    const float Ac  = __expf(-trv * ik);     // e^{-tr/k}
    const float Bc  = __expf( tlv * ik);     // e^{+tl/k}

    f32x4 acc[2][2];
    #pragma unroll
    for (int mi = 0; mi < 2; ++mi)
        #pragma unroll
        for (int fi = 0; fi < 2; ++fi)
            acc[mi][fi] = (f32x4){0.f, 0.f, 0.f, 0.f};

    float XA0[4], XA1[4], XB0[4], XB1[4];    // depth-2 parity prefetch sets
    float T[8];                              // t values (depth-1, L1-hot)
    float dsum = 0.0f;                       // fp32 denominator partial

#define LOADX(X0_, X1_, T_) { \
    const float* p_ = xb + (size_t)((T_) * TL + 2 * lp2) * Ff + fq * 4; \
    *(float4*)(X0_) = *(const float4*)p_; \
    *(float4*)(X1_) = *(const float4*)(p_ + Ff); }

#define LOADT(T_) { \
    *(float4*)&T[0] = *(const float4*)&t_in[(T_) * TL + lqa * 8]; \
    *(float4*)&T[4] = *(const float4*)&t_in[(T_) * TL + lqa * 8 + 4]; }

// stage (convert x + compute alpha) into buffer BUF_ from register set X0_/X1_
#define STAGEX(BUF_, X0_, X1_) { \
    _Pragma("unroll") \
    for (int j = 0; j < 4; ++j) { \
        const float v0 = (X0_)[j], v1 = (X1_)[j]; \
        const u16 h0 = bf16rne(v0), h1 = bf16rne(v1); \
        const u16 s0 = bf16rne(v0 - bf16tof(h0)), s1 = bf16rne(v1 - bf16tof(h1)); \
        const u32 off_ = (u32)(fq * 4 + j) * TLP + wbase; \
        *(u32*)&xh_s[BUF_][off_] = (u32)h0 | ((u32)h1 << 16); \
        *(u32*)&xl_s[BUF_][off_] = (u32)s0 | ((u32)s1 << 16); } \
    u32 hi_[4], lo_[4]; \
    _Pragma("unroll") \
    for (int jj = 0; jj < 8; jj += 2) { \
        const float u0 = __expf(T[jj]     * ik); \
        const float u1 = __expf(T[jj + 1] * ik); \
        const float d0 = fmaf(Ac, u0, 1.0f) * (u0 + Bc); \
        const float d1 = fmaf(Ac, u1, 1.0f) * (u1 + Bc); \
        const float a0 = u0 * __builtin_amdgcn_rcpf(d0); \
        const float a1 = u1 * __builtin_amdgcn_rcpf(d1); \
        dsum += a0 + a1; \
        const u16 h0 = bf16rne(a0), h1 = bf16rne(a1); \
        const u16 s0 = bf16rne(a0 - bf16tof(h0)), s1 = bf16rne(a1 - bf16tof(h1)); \
        hi_[jj >> 1] = (u32)h0 | ((u32)h1 << 16); \
        lo_[jj >> 1] = (u32)s0 | ((u32)s1 << 16); } \
    const u32 aoff_ = (u32)ma * TLP + lqa * 8; \
    *(uint4*)&ah_s[BUF_][aoff_] = make_uint4(hi_[0], hi_[1], hi_[2], hi_[3]); \
    *(uint4*)&al_s[BUF_][aoff_] = make_uint4(lo_[0], lo_[1], lo_[2], lo_[3]); }

// One K-tile: issue t+1 T-load and t+2 x-load early, read fragments, 12 MFMA,
// stage tile t+1 (x from XS set, alpha from T), lgkm-only barrier.
#define TILE(T_, CUR_, XS0_, XS1_, XL0_, XL1_) { \
    if ((T_) + 1 < NT) LOADT((T_) + 1); \
    if ((T_) + 2 < NT) LOADX(XL0_, XL1_, (T_) + 2); \
    short8 ahf[2], alf[2], xhf[2], xlf[2]; \
    _Pragma("unroll") \
    for (int mi = 0; mi < 2; ++mi) { \
        const u32 off_ = (u32)(mh * 32 + mi * 16 + c) * TLP + q * 8; \
        ahf[mi] = *(const short8*)&ah_s[CUR_][off_]; \
        alf[mi] = *(const short8*)&al_s[CUR_][off_]; } \
    _Pragma("unroll") \
    for (int fi = 0; fi < 2; ++fi) { \
        const int row_ = fh * 32 + fi * 16 + c; \
        const u32 off_ = (u32)row_ * TLP + (u32)((q ^ ((row_ >> 3) & 3)) * 8); \
        xhf[fi] = *(const short8*)&xh_s[CUR_][off_]; \
        xlf[fi] = *(const short8*)&xl_s[CUR_][off_]; } \
    _Pragma("unroll") \
    for (int mi = 0; mi < 2; ++mi) \
        _Pragma("unroll") \
        for (int fi = 0; fi < 2; ++fi) { \
            acc[mi][fi] = __builtin_amdgcn_mfma_f32_16x16x32_bf16(ahf[mi], xhf[fi], acc[mi][fi], 0, 0, 0); \
            acc[mi][fi] = __builtin_amdgcn_mfma_f32_16x16x32_bf16(ahf[mi], xlf[fi], acc[mi][fi], 0, 0, 0); \
            acc[mi][fi] = __builtin_amdgcn_mfma_f32_16x16x32_bf16(alf[mi], xhf[fi], acc[mi][fi], 0, 0, 0); } \
    if ((T_) + 1 < NT) STAGEX((CUR_) ^ 1, XS0_, XS1_); \
    lgkm_barrier(); }

    // ---- prologue: stage tile 0, start tile-1 loads ----
    LOADX(XA0, XA1, 0);
    LOADT(0);
    STAGEX(0, XA0, XA1);
    LOADX(XB0, XB1, 1);
    lgkm_barrier();

    // steady state: TILE(t) consumes buf[t&1]; stages t+1 from the set loaded
    // at t-1; issues load of t+2 into the set just freed.
    for (int tt = 0; tt < NT / 2; ++tt) {
        const int t0 = 2 * tt;
        TILE(t0,     0, XB0, XB1, XA0, XA1);
        TILE(t0 + 1, 1, XA0, XA1, XB0, XB1);
    }

#undef TILE
#undef STAGEX
#undef LOADT
#undef LOADX

    // ---- denominator reduce (alias freed stage buf 0) ----
    float* dred = (float*)&xh_s[0][0];       // 256 f32 partials
    float* invp = dred + 256;                // 64 f32 inverses (within 5 KB)
    dred[lqa * 64 + ma] = dsum;
    lgkm_barrier();
    if (tid < Mm) {
        const float d = dred[tid] + dred[64 + tid] + dred[128 + tid] + dred[192 + tid];
        invp[tid] = __builtin_amdgcn_rcpf(d + EPSV);
    }
    lgkm_barrier();

    // ---- epilogue: scale by 1/(denom+eps), store ----
    float* ob = out + (size_t)(b * Nn + n) * (Mm * Ff);
    #pragma unroll
    for (int mi = 0; mi < 2; ++mi) {
        const int mbase = mh * 32 + mi * 16 + q * 4;
        float iv[4];
        #pragma unroll
        for (int r = 0; r < 4; ++r) iv[r] = invp[mbase + r];
        #pragma unroll
        for (int fi = 0; fi < 2; ++fi) {
            const int f = fh * 32 + fi * 16 + c;
            #pragma unroll
            for (int r = 0; r < 4; ++r)
                ob[(size_t)(mbase + r) * Ff + f] = acc[mi][fi][r] * iv[r];
        }
    }
}

extern "C" void kernel_launch(void* const* d_in, const int* in_sizes, int n_in,
                              void* d_out, int out_size, void* d_ws, size_t ws_size,
                              hipStream_t stream)
{
    const float* x_aug   = (const float*)d_in[0];
    const float* t_in    = (const float*)d_in[1];
    const float* t_left  = (const float*)d_in[2];
    const float* t_right = (const float*)d_in[3];
    const float* kappa   = (const float*)d_in[4];
    float* out = (float*)d_out;

    hipLaunchKernelGGL(wagg_fused2, dim3(Bb * Nn), dim3(256), 0, stream,
                       x_aug, t_in, t_left, t_right, kappa, out);
}

// Round 3
// 204.589 us; speedup vs baseline: 1.0593x; 1.0129x over previous
//
#include <hip/hip_runtime.h>
#include <math.h>

typedef unsigned short u16;
typedef unsigned int   u32;
typedef __attribute__((ext_vector_type(8))) short short8;
typedef __attribute__((ext_vector_type(4))) float f32x4;

namespace {
constexpr int Bb = 32, Nn = 32, Ll = 512, Mm = 64, Ff = 64;
constexpr int TL  = 32;           // K-tile in l (= one MFMA K step)
constexpr int NT  = Ll / TL;      // 16
constexpr int TLP = 40;           // padded row (u16): 80B stride
constexpr int FH  = 32;           // f per block (f-split x2)
constexpr float EPSV = 1e-8f;
}

__device__ __forceinline__ u16 bf16rne(float x) {
    u32 u = __float_as_uint(x);
    return (u16)((u + 0x7fffu + ((u >> 16) & 1u)) >> 16);
}
__device__ __forceinline__ float bf16tof(u16 h) {
    return __uint_as_float(((u32)h) << 16);
}

// LDS-only barrier: global loads stay in flight across it.
__device__ __forceinline__ void lgkm_barrier() {
    asm volatile("s_waitcnt lgkmcnt(0)" ::: "memory");
    __builtin_amdgcn_s_barrier();
    asm volatile("" ::: "memory");
}

// ---------------------------------------------------------------------------
// f-split kernel: grid 2048 = (b, n, fhalf).  Each block computes the
// 64m x 32f half-slab of out[b][n].  Rationale (round-2 post-mortem): the old
// grid of 1024 = exactly 4 blocks/CU was GRID-limited occupancy (16 waves/CU,
// one round, no oversubscription) — all throughput fixes were neutral because
// the stalls are latency with nothing to fill them.  This version:
//   - single-buffered LDS 15.4 KB  -> LDS allows 10 blocks/CU
//   - ~70 VGPR, __launch_bounds__(256,6) -> 6 resident blocks = 24 waves/CU
//   - 2048 blocks -> oversubscription, scheduler refills as blocks retire
// alpha math / fragment bytes / MFMA order / dsum order are identical to the
// round-0 kernel => output bit-identical (absmax must stay 0.0009765625).
// x traffic unchanged (disjoint 128B f-slabs); alpha VALU duplicated x2
// (still under the HBM floor, and now better overlapped).
// ---------------------------------------------------------------------------
__global__ __launch_bounds__(256, 6)
void wagg_fsplit(const float* __restrict__ x_aug,
                 const float* __restrict__ t_in,
                 const float* __restrict__ t_left,
                 const float* __restrict__ t_right,
                 const float* __restrict__ kappa,
                 float* __restrict__ out)
{
    const int fhalf = blockIdx.x & 1;
    const int n     = (blockIdx.x >> 1) & 31;
    const int b     = blockIdx.x >> 6;
    const int tid   = threadIdx.x;

    __shared__ u16 ah_s[Mm * TLP];   // alpha-hi [m][l]      5.125 KB
    __shared__ u16 al_s[Mm * TLP];   // alpha-lo             5.125 KB
    __shared__ u16 xh_s[FH * TLP];   // x-hi [f'][l-swz]     2.563 KB
    __shared__ u16 xl_s[FH * TLP];   // x-lo                 2.563 KB

    // ---- x staging ids: one l-row, one f-quad per thread ----
    const int xfq    = tid & 7;      // f-quad within half (f' = 4*xfq + j)
    const int xl     = tid >> 3;     // l within tile, 0..31
    const int xchunk = xl >> 3;      // l chunk (constant per wave)
    const int xrem   = xl & 7;

    // ---- alpha ids (same map as round 0: bit-identical dsum order) ----
    const int wv   = tid >> 6;
    const int lane = tid & 63;
    const int ma   = wv * 16 + (lane >> 2);
    const int lqa  = lane & 3;

    // ---- MFMA ids: wave = (m-half of 32, f-sub of 16) ----
    const int mh = wv & 1;
    const int fh = wv >> 1;          // 0..1 -> f' base = fh*16
    const int q  = lane >> 4;
    const int c  = lane & 15;

    const float* xb = x_aug + (size_t)(b * Nn + n) * (Ll * Ff) + fhalf * FH;

    const float kap = kappa[n];
    const float kk  = fmaxf(kap, 0.0f) + log1pf(expf(-fabsf(kap))); // softplus
    const float ik  = 1.0f / kk;
    const float tlv = t_left [n * Mm + ma];
    const float trv = t_right[n * Mm + ma];
    const float Ac  = __expf(-trv * ik);
    const float Bc  = __expf( tlv * ik);

    f32x4 acc[2];
    acc[0] = (f32x4){0.f, 0.f, 0.f, 0.f};
    acc[1] = (f32x4){0.f, 0.f, 0.f, 0.f};

    float X[4];                      // depth-1 x prefetch (one float4)
    float T[8];
    float dsum = 0.0f;

#define LOADX(T_) { \
    const float* p_ = xb + (size_t)((T_) * TL + xl) * Ff + xfq * 4; \
    *(float4*)X = *(const float4*)p_; }

#define LOADT(T_) { \
    *(float4*)&T[0] = *(const float4*)&t_in[(T_) * TL + lqa * 8]; \
    *(float4*)&T[4] = *(const float4*)&t_in[(T_) * TL + lqa * 8 + 4]; }

// Stage x (hi/lo, chunk-XOR swizzle identical in algebra to round 0's, so the
// LDS image and frag bytes match) + alpha (math byte-identical to round 0).
#define STAGE() { \
    _Pragma("unroll") \
    for (int j = 0; j < 4; ++j) { \
        const float v = X[j]; \
        const u16 h = bf16rne(v); \
        const u16 s = bf16rne(v - bf16tof(h)); \
        const int row_ = xfq * 4 + j; \
        const u32 off_ = (u32)row_ * TLP \
                       + (u32)(((xchunk ^ ((row_ >> 3) & 3)) * 8) + xrem); \
        xh_s[off_] = h; \
        xl_s[off_] = s; } \
    u32 hi_[4], lo_[4]; \
    _Pragma("unroll") \
    for (int jj = 0; jj < 8; jj += 2) { \
        const float u0 = __expf(T[jj]     * ik); \
        const float u1 = __expf(T[jj + 1] * ik); \
        const float d0 = fmaf(Ac, u0, 1.0f) * (u0 + Bc); \
        const float d1 = fmaf(Ac, u1, 1.0f) * (u1 + Bc); \
        const float a0 = u0 * __builtin_amdgcn_rcpf(d0); \
        const float a1 = u1 * __builtin_amdgcn_rcpf(d1); \
        dsum += a0 + a1; \
        const u16 h0 = bf16rne(a0), h1 = bf16rne(a1); \
        const u16 s0 = bf16rne(a0 - bf16tof(h0)), s1 = bf16rne(a1 - bf16tof(h1)); \
        hi_[jj >> 1] = (u32)h0 | ((u32)h1 << 16); \
        lo_[jj >> 1] = (u32)s0 | ((u32)s1 << 16); } \
    const u32 aoff_ = (u32)ma * TLP + lqa * 8; \
    *(uint4*)&ah_s[aoff_] = make_uint4(hi_[0], hi_[1], hi_[2], hi_[3]); \
    *(uint4*)&al_s[aoff_] = make_uint4(lo_[0], lo_[1], lo_[2], lo_[3]); }

    // ---- prologue: stage tile 0 ----
    LOADX(0);
    LOADT(0);
    STAGE();
    lgkm_barrier();

    // ---- main loop: single buffer, 2 lgkm barriers per tile ----
    for (int t = 0; t < NT; ++t) {
        if (t + 1 < NT) { LOADX(t + 1); LOADT(t + 1); }

        short8 ahf[2], alf[2], xhf, xlf;
        #pragma unroll
        for (int mi = 0; mi < 2; ++mi) {
            const u32 off = (u32)(mh * 32 + mi * 16 + c) * TLP + q * 8;
            ahf[mi] = *(const short8*)&ah_s[off];
            alf[mi] = *(const short8*)&al_s[off];
        }
        {
            const int row = fh * 16 + c;
            const u32 off = (u32)row * TLP + (u32)((q ^ ((row >> 3) & 3)) * 8);
            xhf = *(const short8*)&xh_s[off];
            xlf = *(const short8*)&xl_s[off];
        }
        lgkm_barrier();              // all frag reads complete; buffer free

        #pragma unroll
        for (int mi = 0; mi < 2; ++mi) {
            acc[mi] = __builtin_amdgcn_mfma_f32_16x16x32_bf16(ahf[mi], xhf, acc[mi], 0, 0, 0);
            acc[mi] = __builtin_amdgcn_mfma_f32_16x16x32_bf16(ahf[mi], xlf, acc[mi], 0, 0, 0);
            acc[mi] = __builtin_amdgcn_mfma_f32_16x16x32_bf16(alf[mi], xhf, acc[mi], 0, 0, 0);
        }

        if (t + 1 < NT) STAGE();     // overwrite buffer with tile t+1
        lgkm_barrier();              // writes visible for next iteration
    }

    // ---- denominator reduce (alias freed x buffer; all reads drained) ----
    float* dred = (float*)&xh_s[0];  // 256 f32 partials (1 KB of 2.56 KB)
    float* invp = dred + 256;        // 64 f32 inverses
    dred[lqa * 64 + ma] = dsum;
    lgkm_barrier();
    if (tid < Mm) {
        const float d = dred[tid] + dred[64 + tid] + dred[128 + tid] + dred[192 + tid];
        invp[tid] = __builtin_amdgcn_rcpf(d + EPSV);
    }
    lgkm_barrier();

    // ---- epilogue ----
    float* ob = out + (size_t)(b * Nn + n) * (Mm * Ff) + fhalf * FH;
    #pragma unroll
    for (int mi = 0; mi < 2; ++mi) {
        const int mbase = mh * 32 + mi * 16 + q * 4;
        float iv[4];
        #pragma unroll
        for (int r = 0; r < 4; ++r) iv[r] = invp[mbase + r];
        const int f = fh * 16 + c;
        #pragma unroll
        for (int r = 0; r < 4; ++r)
            ob[(size_t)(mbase + r) * Ff + f] = acc[mi][r] * iv[r];
    }

#undef STAGE
#undef LOADT
#undef LOADX
}

extern "C" void kernel_launch(void* const* d_in, const int* in_sizes, int n_in,
                              void* d_out, int out_size, void* d_ws, size_t ws_size,
                              hipStream_t stream)
{
    const float* x_aug   = (const float*)d_in[0];
    const float* t_in    = (const float*)d_in[1];
    const float* t_left  = (const float*)d_in[2];
    const float* t_right = (const float*)d_in[3];
    const float* kappa   = (const float*)d_in[4];
    float* out = (float*)d_out;

    hipLaunchKernelGGL(wagg_fsplit, dim3(Bb * Nn * 2), dim3(256), 0, stream,
                       x_aug, t_in, t_left, t_right, kappa, out);
}